// Round 1
// baseline (56.117 us; speedup 1.0000x reference)
//
#include <hip/hip_runtime.h>

// FK over the SMPL joint tree: 6D -> rotmat (Gram-Schmidt), then
// R_global[i] = R_global[parent[i]] @ R_local[i]; output rows 0..1 of each.
// One thread per frame; parent tree hardcoded (compile-time constant in the
// reference), fully unrolled so Rg[][] is statically indexed -> registers.

__global__ __launch_bounds__(256) void fk6d_kernel(const float* __restrict__ in,
                                                   float* __restrict__ out,
                                                   int N)
{
    constexpr int PAR[22] = {0, 0, 0, 0, 1, 2, 3, 4, 5, 6, 7, 8, 9, 9, 9,
                             12, 13, 14, 16, 17, 18, 19};
    int n = blockIdx.x * blockDim.x + threadIdx.x;
    if (n >= N) return;
    const float* __restrict__ p = in + (size_t)n * 132;
    float* __restrict__ o = out + (size_t)n * 132;

    float Rg[22][9];

#pragma unroll
    for (int j = 0; j < 22; ++j) {
        // 6 input floats for this joint; frame base is 16B-aligned,
        // 24*j byte offset keeps 8B alignment -> float2 loads are safe.
        float2 d0 = *reinterpret_cast<const float2*>(p + 6 * j);
        float2 d1 = *reinterpret_cast<const float2*>(p + 6 * j + 2);
        float2 d2 = *reinterpret_cast<const float2*>(p + 6 * j + 4);
        float a1x = d0.x, a1y = d0.y, a1z = d1.x;
        float a2x = d1.y, a2y = d2.x, a2z = d2.y;

        // Gram-Schmidt: b1 = a1/|a1|; b2 = normalize(a2 - (b1.a2) b1); b3 = b1 x b2
        float n1 = sqrtf(a1x * a1x + a1y * a1y + a1z * a1z);
        float i1 = 1.0f / fmaxf(n1, 1e-12f);
        float b1x = a1x * i1, b1y = a1y * i1, b1z = a1z * i1;

        float dt = b1x * a2x + b1y * a2y + b1z * a2z;
        float cx = a2x - dt * b1x;
        float cy = a2y - dt * b1y;
        float cz = a2z - dt * b1z;
        float n2 = sqrtf(cx * cx + cy * cy + cz * cz);
        float i2 = 1.0f / fmaxf(n2, 1e-12f);
        float b2x = cx * i2, b2y = cy * i2, b2z = cz * i2;

        float b3x = b1y * b2z - b1z * b2y;
        float b3y = b1z * b2x - b1x * b2z;
        float b3z = b1x * b2y - b1y * b2x;

        // local rotation rows: r0=b1, r1=b2, r2=b3
        float L[9] = {b1x, b1y, b1z, b2x, b2y, b2z, b3x, b3y, b3z};

        float* G = Rg[j];
        if (j == 0) {
#pragma unroll
            for (int k = 0; k < 9; ++k) G[k] = L[k];
        } else {
            const float* P = Rg[PAR[j]];  // PAR[j] is compile-time: static index
#pragma unroll
            for (int r = 0; r < 3; ++r) {
#pragma unroll
                for (int c = 0; c < 3; ++c) {
                    G[3 * r + c] = P[3 * r + 0] * L[0 + c] +
                                   P[3 * r + 1] * L[3 + c] +
                                   P[3 * r + 2] * L[6 + c];
                }
            }
        }

        // output = rows 0 and 1 of G (6 floats), same layout as input
        float2 s0 = {G[0], G[1]};
        float2 s1 = {G[2], G[3]};
        float2 s2 = {G[4], G[5]};
        *reinterpret_cast<float2*>(o + 6 * j) = s0;
        *reinterpret_cast<float2*>(o + 6 * j + 2) = s1;
        *reinterpret_cast<float2*>(o + 6 * j + 4) = s2;
    }
}

extern "C" void kernel_launch(void* const* d_in, const int* in_sizes, int n_in,
                              void* d_out, int out_size, void* d_ws, size_t ws_size,
                              hipStream_t stream) {
    const float* in = (const float*)d_in[0];
    float* out = (float*)d_out;
    int N = in_sizes[0] / 132;  // B*T frames
    int block = 256;
    int grid = (N + block - 1) / block;
    fk6d_kernel<<<grid, block, 0, stream>>>(in, out, N);
}

// Round 2
// 40.947 us; speedup vs baseline: 1.3705x; 1.3705x over previous
//
#include <hip/hip_runtime.h>

// FK over the SMPL joint tree, LDS-transposed for coalescing.
// Block = 128 threads stages 128 frames (132 f32 each, padded row stride 133
// -> stride mod 32 banks = 5, conflict-free) via coalesced 4B loads, computes
// one frame per thread from LDS (Gram-Schmidt 6D->rotmat + parent-chain
// matmul, fully unrolled so Rg[][] is statically indexed -> registers),
// writes the 6 output floats per joint back IN PLACE into the same LDS row
// (joint-j input is consumed before joint-j output is written; each row is
// owned by exactly one thread), then stores coalesced.

#define FPB 128            // frames per block == threads per block
#define FLOATS_PER_FRAME 132
#define LDS_STRIDE 133     // +1 pad: 133 % 32 = 5 -> conflict-free lane access

__global__ __launch_bounds__(FPB) void fk6d_kernel(const float* __restrict__ in,
                                                   float* __restrict__ out,
                                                   int N)
{
    constexpr int PAR[22] = {0, 0, 0, 0, 1, 2, 3, 4, 5, 6, 7, 8, 9, 9, 9,
                             12, 13, 14, 16, 17, 18, 19};
    __shared__ float lds[FPB * LDS_STRIDE];

    const int tid = threadIdx.x;
    const int block_frame0 = blockIdx.x * FPB;
    const int frames_here = min(FPB, N - block_frame0);
    const size_t gbase = (size_t)block_frame0 * FLOATS_PER_FRAME;
    const int total = frames_here * FLOATS_PER_FRAME;

    // ---- coalesced load: global -> LDS (padded transpose-friendly layout)
    for (int idx = tid; idx < total; idx += FPB) {
        int f = idx / FLOATS_PER_FRAME;          // magic-mul, ~3 VALU
        int m = idx - f * FLOATS_PER_FRAME;
        lds[f * LDS_STRIDE + m] = in[gbase + idx];
    }
    __syncthreads();

    // ---- compute: one frame per thread, entirely from/to LDS registers
    if (tid < frames_here) {
        float* __restrict__ row = &lds[tid * LDS_STRIDE];
        float Rg[22][9];

#pragma unroll
        for (int j = 0; j < 22; ++j) {
            float a1x = row[6 * j + 0], a1y = row[6 * j + 1], a1z = row[6 * j + 2];
            float a2x = row[6 * j + 3], a2y = row[6 * j + 4], a2z = row[6 * j + 5];

            // Gram-Schmidt: b1 = a1/|a1|; b2 = normalize(a2 - (b1.a2)b1); b3 = b1 x b2
            float n1 = sqrtf(a1x * a1x + a1y * a1y + a1z * a1z);
            float i1 = 1.0f / fmaxf(n1, 1e-12f);
            float b1x = a1x * i1, b1y = a1y * i1, b1z = a1z * i1;

            float dt = b1x * a2x + b1y * a2y + b1z * a2z;
            float cx = a2x - dt * b1x;
            float cy = a2y - dt * b1y;
            float cz = a2z - dt * b1z;
            float n2 = sqrtf(cx * cx + cy * cy + cz * cz);
            float i2 = 1.0f / fmaxf(n2, 1e-12f);
            float b2x = cx * i2, b2y = cy * i2, b2z = cz * i2;

            float b3x = b1y * b2z - b1z * b2y;
            float b3y = b1z * b2x - b1x * b2z;
            float b3z = b1x * b2y - b1y * b2x;

            float L[9] = {b1x, b1y, b1z, b2x, b2y, b2z, b3x, b3y, b3z};

            float* G = Rg[j];
            if (j == 0) {
#pragma unroll
                for (int k = 0; k < 9; ++k) G[k] = L[k];
            } else {
                const float* P = Rg[PAR[j]];  // compile-time index -> registers
#pragma unroll
                for (int r = 0; r < 3; ++r) {
#pragma unroll
                    for (int c = 0; c < 3; ++c) {
                        G[3 * r + c] = P[3 * r + 0] * L[0 + c] +
                                       P[3 * r + 1] * L[3 + c] +
                                       P[3 * r + 2] * L[6 + c];
                    }
                }
            }

            // output rows 0..1 of G, in place over this joint's input slot
            row[6 * j + 0] = G[0];
            row[6 * j + 1] = G[1];
            row[6 * j + 2] = G[2];
            row[6 * j + 3] = G[3];
            row[6 * j + 4] = G[4];
            row[6 * j + 5] = G[5];
        }
    }
    __syncthreads();

    // ---- coalesced store: LDS -> global
    for (int idx = tid; idx < total; idx += FPB) {
        int f = idx / FLOATS_PER_FRAME;
        int m = idx - f * FLOATS_PER_FRAME;
        out[gbase + idx] = lds[f * LDS_STRIDE + m];
    }
}

extern "C" void kernel_launch(void* const* d_in, const int* in_sizes, int n_in,
                              void* d_out, int out_size, void* d_ws, size_t ws_size,
                              hipStream_t stream) {
    const float* in = (const float*)d_in[0];
    float* out = (float*)d_out;
    int N = in_sizes[0] / FLOATS_PER_FRAME;  // B*T frames
    int grid = (N + FPB - 1) / FPB;
    fk6d_kernel<<<grid, FPB, 0, stream>>>(in, out, N);
}